// Round 4
// baseline (200.089 us; speedup 1.0000x reference)
//
#include <hip/hip_runtime.h>
#include <hip/hip_bf16.h>

typedef __bf16 bf16x8 __attribute__((ext_vector_type(8)));
typedef float  f32x16 __attribute__((ext_vector_type(16)));
typedef float  f32x4  __attribute__((ext_vector_type(4)));
typedef float  f32x2  __attribute__((ext_vector_type(2)));

static __device__ __forceinline__ f32x16 mfma32(bf16x8 a, bf16x8 b, f32x16 c) {
    return __builtin_amdgcn_mfma_f32_32x32x16_bf16(a, b, c, 0, 0, 0);
}

// gelu-tanh via sigmoid with log2e folded in:
// gelu(h) = h / (1 + exp2(-h*(C1 + C2*h^2)))
#define GELU_C1 2.30220820f
#define GELU_C2 0.10294324f

// ---------------------------------------------------------------------------
// Pack kernel (unchanged from round 3).
// W1p (K=144, bias folded as k=128 row), W2p sigma-permuted for direct
// GEMM1-frag -> GEMM2-A-frag feed.
// ---------------------------------------------------------------------------
__global__ __launch_bounds__(256) void pack_kernel(
    const float* __restrict__ We1, const float* __restrict__ be1,
    const float* __restrict__ Ws1, const float* __restrict__ bs1,
    const float* __restrict__ We2, const float* __restrict__ Ws2,
    __bf16* __restrict__ w1p, __bf16* __restrict__ w2p)
{
    int tid = blockIdx.x * 256 + threadIdx.x;
    if (tid < 23040) {
        int l  = tid & 63;
        int ks = (tid >> 6) % 9;
        int nt = (tid / 576) & 3;
        int e  = tid / 2304;
        const float* src = (e < 8) ? (We1 + e * 16384) : (Ws1 + (e - 8) * 16384);
        const float* bia = (e < 8) ? (be1 + e * 128)   : (bs1 + (e - 8) * 128);
        int n = nt * 32 + (l & 31);
        int kb = ks * 16 + (l >> 5) * 8;
        bf16x8 v;
        #pragma unroll
        for (int j = 0; j < 8; ++j) {
            int k = kb + j;
            float f = (k < 128) ? src[k * 128 + n] : ((k == 128) ? bia[n] : 0.f);
            v[j] = (__bf16)f;
        }
        *(bf16x8*)(w1p + (size_t)tid * 8) = v;
    } else if (tid < 43520) {
        int t2 = tid - 23040;
        int l  = t2 & 63;
        int ks = (t2 >> 6) & 7;
        int ot = (t2 / 512) & 3;
        int e  = t2 / 2048;
        const float* src = (e < 8) ? (We2 + e * 16384) : (Ws2 + (e - 8) * 16384);
        int o  = ot * 32 + (l & 31);
        int lh = l >> 5;
        bf16x8 v;
        #pragma unroll
        for (int j = 0; j < 8; ++j) {
            int hid = 16 * ks + 8 * (j >> 2) + 4 * lh + (j & 3);
            v[j] = (__bf16)src[hid * 128 + o];
        }
        *(bf16x8*)(w2p + (size_t)t2 * 8) = v;
    }
}

// ---------------------------------------------------------------------------
// Fused MoE kernel: router (fp64, bit-identical op order to the verified
// standalone router) + expert loop, 64 tokens per block, 4 waves.
// LDS: xs (fp32 x rows, router input) | Xp (bf16 MFMA frags) | rfs (fp64
// router features) | mgs (fp32 gates). Red overlays xs after the expert loop.
// ---------------------------------------------------------------------------
__global__ __launch_bounds__(256, 2) void moe_main_kernel(
    const float* __restrict__ x,
    const float* __restrict__ Wr1, const float* __restrict__ br1,
    const float* __restrict__ Wr2, const float* __restrict__ br2,
    const __bf16* __restrict__ w1p, const __bf16* __restrict__ w2p,
    const float* __restrict__ be2, const float* __restrict__ bs2,
    float* __restrict__ out)
{
    __shared__ __align__(16) char lds[62464];
    float*  xs  = (float*)lds;                       // 64*132*4 = 33792 B
    __bf16* Xp  = (__bf16*)(lds + 33792);            // 18432 B
    double* rfs = (double*)(lds + 33792 + 18432);    // 64*16*8 = 8192 B
    float*  mgs = (float*)(lds + 33792 + 18432 + 8192); // 64*8*4 = 2048 B
    float*  Red = (float*)lds;                       // overlay after expert loop

    const int t    = threadIdx.x;
    const int lane = t & 63;
    const int wave = t >> 6;
    const int l31  = lane & 31;
    const int lh   = lane >> 5;
    const int mt   = wave >> 1;
    const int h    = wave & 1;
    const int tok0 = blockIdx.x * 64;

    // ---- stage X: one global read builds fp32 xs (router) + bf16 Xp frags ----
    #pragma unroll
    for (int i = 0; i < 4; ++i) {
        int g = i * 256 + t;       // 8-element group id, 0..1023
        int m = g >> 4;            // token 0..63
        int c = g & 15;            // which 8-k chunk
        const f32x4* sp = (const f32x4*)(x + (size_t)(tok0 + m) * 128 + c * 8);
        f32x4 va = sp[0], vb = sp[1];
        *(f32x4*)&xs[m * 132 + c * 8]     = va;
        *(f32x4*)&xs[m * 132 + c * 8 + 4] = vb;
        bf16x8 v;
        v[0]=(__bf16)va[0]; v[1]=(__bf16)va[1]; v[2]=(__bf16)va[2]; v[3]=(__bf16)va[3];
        v[4]=(__bf16)vb[0]; v[5]=(__bf16)vb[1]; v[6]=(__bf16)vb[2]; v[7]=(__bf16)vb[3];
        *(bf16x8*)&Xp[(((m >> 5) * 9 + (c >> 1)) * 64 + (c & 1) * 32 + (m & 31)) * 8] = v;
    }
    // ks=8 bias column: k=128 -> 1.0, k=129..143 -> 0
    if (t < 128) {
        int mtx = t >> 6, l = t & 63;
        bf16x8 v;
        #pragma unroll
        for (int j = 0; j < 8; ++j) v[j] = (__bf16)0.f;
        if (l < 32) v[0] = (__bf16)1.0f;
        *(bf16x8*)&Xp[((mtx * 9 + 8) * 64 + l) * 8] = v;
    }
    __syncthreads();

    // ---- router layer 1 (fp64): thread (tok = t&63, rq = t>>6) computes 4 rf ----
    {
        const int tok = t & 63;
        const int rq  = (t >> 6) * 4;     // wave-uniform -> Wr1 reads are s_loads
        double rf4[4];
        #pragma unroll
        for (int j = 0; j < 4; ++j) rf4[j] = (double)br1[rq + j];
        const f32x4* xr = (const f32x4*)(xs + tok * 132);
        for (int c = 0; c < 32; ++c) {
            f32x4 xv4 = xr[c];
            #pragma unroll
            for (int q = 0; q < 4; ++q) {
                double xv = (double)xv4[q];
                int k = c * 4 + q;
                #pragma unroll
                for (int j = 0; j < 4; ++j)
                    rf4[j] = fma(xv, (double)Wr1[k * 16 + rq + j], rf4[j]);
            }
        }
        #pragma unroll
        for (int j = 0; j < 4; ++j)
            rfs[tok * 16 + rq + j] = rf4[j] > 0.0 ? rf4[j] : 0.0;
    }
    __syncthreads();

    // ---- router layer 2 + softmax + mask (fp64), one thread per token ----
    if (t < 64) {
        double lg[8];
        #pragma unroll
        for (int j = 0; j < 8; ++j) lg[j] = (double)br2[j];
        #pragma unroll
        for (int r = 0; r < 16; ++r) {
            double rv = rfs[t * 16 + r];
            #pragma unroll
            for (int j = 0; j < 8; ++j)
                lg[j] = fma(rv, (double)Wr2[r * 8 + j], lg[j]);
        }
        double mx = lg[0];
        #pragma unroll
        for (int j = 1; j < 8; ++j) mx = lg[j] > mx ? lg[j] : mx;
        double ex[8]; double s = 0.0;
        #pragma unroll
        for (int j = 0; j < 8; ++j) { ex[j] = exp(lg[j] - mx); s += ex[j]; }
        double mv[8]; double ms = 0.0;
        #pragma unroll
        for (int j = 0; j < 8; ++j) {
            double g = ex[j] / s;
            double m = (g > 0.125) ? g : 0.0;
            mv[j] = m; ms += m;
        }
        double inv = 1.0 / (ms + 1e-8);
        #pragma unroll
        for (int j = 0; j < 8; ++j) mgs[t * 8 + j] = (float)(mv[j] * inv);
    }
    __syncthreads();

    // ---- per-token gates for this wave's token tile ----
    const float* mgr = mgs + (32 * mt + l31) * 8;
    f32x4 ga4 = *(const f32x4*)mgr;
    f32x4 gb4 = *(const f32x4*)(mgr + 4);
    float gte[8] = {ga4[0], ga4[1], ga4[2], ga4[3], gb4[0], gb4[1], gb4[2], gb4[3]};

    f32x16 acc[4];
    #pragma unroll
    for (int ot = 0; ot < 4; ++ot)
        #pragma unroll
        for (int i = 0; i < 16; ++i) acc[ot][i] = 0.f;

    const bf16x8* w1v = (const bf16x8*)w1p;
    const bf16x8* w2v = (const bf16x8*)w2p;

    #pragma unroll 1
    for (int e = 0; e < 10; ++e) {
        // W1^T A-frags for n-tiles 2h, 2h+1 (9 ks each, bias row included)
        const bf16x8* wap = w1v + ((size_t)(e * 4 + 2 * h) * 9) * 64 + lane;
        bf16x8 wa[9], wb[9];
        #pragma unroll
        for (int ks = 0; ks < 9; ++ks) { wa[ks] = wap[ks * 64]; wb[ks] = wap[(9 + ks) * 64]; }

        // issue W2 B-frag loads now: latency hides under GEMM1 + gelu
        const bf16x8* wBp = w2v + ((size_t)(e * 4) * 8 + 4 * h) * 64 + lane;
        bf16x8 wB[4][4];
        #pragma unroll
        for (int ot = 0; ot < 4; ++ot)
            #pragma unroll
            for (int kq = 0; kq < 4; ++kq)
                wB[ot][kq] = wBp[(ot * 8 + kq) * 64];

        f32x16 a1[2];
        #pragma unroll
        for (int n2 = 0; n2 < 2; ++n2)
            #pragma unroll
            for (int i = 0; i < 16; ++i) a1[n2][i] = 0.f;

        #pragma unroll
        for (int ks = 0; ks < 9; ++ks) {
            bf16x8 xb = *(const bf16x8*)&Xp[((mt * 9 + ks) * 64 + lane) * 8];
            a1[0] = mfma32(wa[ks], xb, a1[0]);
            a1[1] = mfma32(wb[ks], xb, a1[1]);
        }

        const float gv = (e < 8) ? gte[e] : 1.0f;

        // gelu + gate -> A-frags -> GEMM2 (sigma-permuted, no data movement)
        #pragma unroll
        for (int n2 = 0; n2 < 2; ++n2) {
            #pragma unroll
            for (int b = 0; b < 2; ++b) {
                bf16x8 fr;
                #pragma unroll
                for (int jp = 0; jp < 4; ++jp) {
                    f32x2 hh; hh[0] = a1[n2][8 * b + 2 * jp]; hh[1] = a1[n2][8 * b + 2 * jp + 1];
                    f32x2 tt = hh * hh;
                    f32x2 pp;
                    pp[0] = fmaf(tt[0], -GELU_C2, -GELU_C1);
                    pp[1] = fmaf(tt[1], -GELU_C2, -GELU_C1);
                    f32x2 mm = hh * pp;
                    float e0 = __builtin_amdgcn_exp2f(mm[0]);
                    float e1 = __builtin_amdgcn_exp2f(mm[1]);
                    float q0 = __builtin_amdgcn_rcpf(1.f + e0);
                    float q1 = __builtin_amdgcn_rcpf(1.f + e1);
                    f32x2 gg; gg[0] = hh[0] * q0 * gv; gg[1] = hh[1] * q1 * gv;
                    fr[2 * jp]     = (__bf16)gg[0];
                    fr[2 * jp + 1] = (__bf16)gg[1];
                }
                int kq = 2 * n2 + b;
                acc[0] = mfma32(fr, wB[0][kq], acc[0]);
                acc[1] = mfma32(fr, wB[1][kq], acc[1]);
                acc[2] = mfma32(fr, wB[2][kq], acc[2]);
                acc[3] = mfma32(fr, wB[3][kq], acc[3]);
            }
        }
    }

    __syncthreads();   // all waves done with xs/Xp; Red overlay now safe
    if (h == 1) {
        #pragma unroll
        for (int ot = 0; ot < 4; ++ot)
            #pragma unroll
            for (int r = 0; r < 16; ++r)
                Red[((mt * 4 + ot) * 16 + r) * 64 + lane] = acc[ot][r];
    }
    __syncthreads();
    if (h == 0) {
        float be2c[4][8], bsc[4];
        #pragma unroll
        for (int ot = 0; ot < 4; ++ot) {
            int o = 32 * ot + l31;
            bsc[ot] = bs2[o] + bs2[128 + o];
            #pragma unroll
            for (int ee = 0; ee < 8; ++ee) be2c[ot][ee] = be2[ee * 128 + o];
        }
        const float* mgb = mgs + (32 * mt) * 8;
        #pragma unroll
        for (int r = 0; r < 16; ++r) {
            int mrow = (r & 3) + 8 * (r >> 2) + 4 * lh;
            f32x4 g0 = *(const f32x4*)&mgb[mrow * 8];
            f32x4 g1 = *(const f32x4*)&mgb[mrow * 8 + 4];
            size_t orow = (size_t)(tok0 + 32 * mt + mrow) * 128;
            #pragma unroll
            for (int ot = 0; ot < 4; ++ot) {
                float b = bsc[ot];
                #pragma unroll
                for (int ee = 0; ee < 4; ++ee) b = fmaf(g0[ee], be2c[ot][ee], b);
                #pragma unroll
                for (int ee = 0; ee < 4; ++ee) b = fmaf(g1[ee], be2c[ot][4 + ee], b);
                float v = acc[ot][r] + Red[((mt * 4 + ot) * 16 + r) * 64 + lane] + b;
                out[orow + 32 * ot + l31] = v;
            }
        }
    }
}

// ---------------------------------------------------------------------------
extern "C" void kernel_launch(void* const* d_in, const int* in_sizes, int n_in,
                              void* d_out, int out_size, void* d_ws, size_t ws_size,
                              hipStream_t stream)
{
    const float* x   = (const float*)d_in[0];
    const float* Wr1 = (const float*)d_in[1];
    const float* br1 = (const float*)d_in[2];
    const float* Wr2 = (const float*)d_in[3];
    const float* br2 = (const float*)d_in[4];
    const float* We1 = (const float*)d_in[5];
    const float* be1 = (const float*)d_in[6];
    const float* We2 = (const float*)d_in[7];
    const float* be2 = (const float*)d_in[8];
    const float* Ws1 = (const float*)d_in[9];
    const float* bs1 = (const float*)d_in[10];
    const float* Ws2 = (const float*)d_in[11];
    const float* bs2 = (const float*)d_in[12];

    // ws: [0,368640) W1p bf16 (K=144, bias folded); [368640,696320) W2p bf16
    __bf16* w1p = (__bf16*)d_ws;
    __bf16* w2p = (__bf16*)((char*)d_ws + 368640);

    pack_kernel<<<170, 256, 0, stream>>>(We1, be1, Ws1, bs1, We2, Ws2, w1p, w2p);
    moe_main_kernel<<<1024, 256, 0, stream>>>(x, Wr1, br1, Wr2, br2,
                                              w1p, w2p, be2, bs2, (float*)d_out);
}

// Round 5
// 176.451 us; speedup vs baseline: 1.1340x; 1.1340x over previous
//
#include <hip/hip_runtime.h>
#include <hip/hip_bf16.h>

typedef __bf16 bf16x8 __attribute__((ext_vector_type(8)));
typedef float  f32x16 __attribute__((ext_vector_type(16)));
typedef float  f32x4  __attribute__((ext_vector_type(4)));
typedef float  f32x2  __attribute__((ext_vector_type(2)));

static __device__ __forceinline__ f32x16 mfma32(bf16x8 a, bf16x8 b, f32x16 c) {
    return __builtin_amdgcn_mfma_f32_32x32x16_bf16(a, b, c, 0, 0, 0);
}

// gelu-tanh via sigmoid with log2e folded in:
// gelu(h) = h / (1 + exp2(-h*(C1 + C2*h^2)))
#define GELU_C1 2.30220820f
#define GELU_C2 0.10294324f

// ---------------------------------------------------------------------------
// Pack kernel: W1p (K=144, bias folded), W2p (sigma-permuted), plus router
// weights converted to fp64 (so the main kernel's router phase does pure
// s_load_dwordx2 + v_fma_f64 with no per-use converts).
// ---------------------------------------------------------------------------
__global__ __launch_bounds__(256) void pack_kernel(
    const float* __restrict__ We1, const float* __restrict__ be1,
    const float* __restrict__ Ws1, const float* __restrict__ bs1,
    const float* __restrict__ We2, const float* __restrict__ Ws2,
    const float* __restrict__ Wr1, const float* __restrict__ br1,
    const float* __restrict__ Wr2, const float* __restrict__ br2,
    __bf16* __restrict__ w1p, __bf16* __restrict__ w2p,
    double* __restrict__ wr1d, double* __restrict__ br1d,
    double* __restrict__ wr2d, double* __restrict__ br2d)
{
    int tid = blockIdx.x * 256 + threadIdx.x;
    if (tid < 23040) {
        int l  = tid & 63;
        int ks = (tid >> 6) % 9;
        int nt = (tid / 576) & 3;
        int e  = tid / 2304;
        const float* src = (e < 8) ? (We1 + e * 16384) : (Ws1 + (e - 8) * 16384);
        const float* bia = (e < 8) ? (be1 + e * 128)   : (bs1 + (e - 8) * 128);
        int n = nt * 32 + (l & 31);
        int kb = ks * 16 + (l >> 5) * 8;
        bf16x8 v;
        #pragma unroll
        for (int j = 0; j < 8; ++j) {
            int k = kb + j;
            float f = (k < 128) ? src[k * 128 + n] : ((k == 128) ? bia[n] : 0.f);
            v[j] = (__bf16)f;
        }
        *(bf16x8*)(w1p + (size_t)tid * 8) = v;
    } else if (tid < 43520) {
        int t2 = tid - 23040;
        int l  = t2 & 63;
        int ks = (t2 >> 6) & 7;
        int ot = (t2 / 512) & 3;
        int e  = t2 / 2048;
        const float* src = (e < 8) ? (We2 + e * 16384) : (Ws2 + (e - 8) * 16384);
        int o  = ot * 32 + (l & 31);
        int lh = l >> 5;
        bf16x8 v;
        #pragma unroll
        for (int j = 0; j < 8; ++j) {
            int hid = 16 * ks + 8 * (j >> 2) + 4 * lh + (j & 3);
            v[j] = (__bf16)src[hid * 128 + o];
        }
        *(bf16x8*)(w2p + (size_t)t2 * 8) = v;
    } else if (tid < 45568) {
        int i = tid - 43520;            // 0..2047: Wr1 [128][16]
        wr1d[i] = (double)Wr1[i];
    } else if (tid < 45696) {
        int i = tid - 45568;            // 0..127: Wr2 [16][8]
        wr2d[i] = (double)Wr2[i];
    } else if (tid < 45712) {
        int i = tid - 45696;            // 0..15
        br1d[i] = (double)br1[i];
    } else if (tid < 45720) {
        int i = tid - 45712;            // 0..7
        br2d[i] = (double)br2[i];
    }
}

// ---------------------------------------------------------------------------
// Fused MoE kernel: fp64 router (decision-exact) + double-buffered expert
// loop. 64 tokens per block, 4 waves.
// ---------------------------------------------------------------------------
__global__ __launch_bounds__(256, 2) void moe_main_kernel(
    const float* __restrict__ x,
    const double* __restrict__ wr1d, const double* __restrict__ br1d,
    const double* __restrict__ wr2d, const double* __restrict__ br2d,
    const __bf16* __restrict__ w1p, const __bf16* __restrict__ w2p,
    const float* __restrict__ be2, const float* __restrict__ bs2,
    float* __restrict__ out)
{
    __shared__ __align__(16) char lds[61952];
    float*  xs  = (float*)lds;                 // 64 rows * 130 f32 = 33280 B
    __bf16* Xp  = (__bf16*)(lds + 33280);      // 18432 B
    double* rfs = (double*)(lds + 51712);      // 64*16*8 = 8192 B
    float*  mgs = (float*)(lds + 59904);       // 64*8*4 = 2048 B
    float*  Red = (float*)lds;                 // overlay after expert loop

    const int t    = threadIdx.x;
    const int lane = t & 63;
    const int wave = t >> 6;
    const int l31  = lane & 31;
    const int lh   = lane >> 5;
    const int mt   = wave >> 1;
    const int h    = wave & 1;
    const int tok0 = blockIdx.x * 64;

    // ---- stage X: one global read builds fp32 xs (stride 130) + bf16 Xp ----
    #pragma unroll
    for (int i = 0; i < 4; ++i) {
        int g = i * 256 + t;       // 8-element group id, 0..1023
        int m = g >> 4;            // token 0..63
        int c = g & 15;            // which 8-k chunk
        const f32x4* sp = (const f32x4*)(x + (size_t)(tok0 + m) * 128 + c * 8);
        f32x4 va = sp[0], vb = sp[1];
        float* xd = xs + m * 130 + c * 8;
        f32x2 s0, s1, s2, s3;
        s0[0]=va[0]; s0[1]=va[1]; s1[0]=va[2]; s1[1]=va[3];
        s2[0]=vb[0]; s2[1]=vb[1]; s3[0]=vb[2]; s3[1]=vb[3];
        *(f32x2*)(xd)     = s0; *(f32x2*)(xd + 2) = s1;
        *(f32x2*)(xd + 4) = s2; *(f32x2*)(xd + 6) = s3;
        bf16x8 v;
        v[0]=(__bf16)va[0]; v[1]=(__bf16)va[1]; v[2]=(__bf16)va[2]; v[3]=(__bf16)va[3];
        v[4]=(__bf16)vb[0]; v[5]=(__bf16)vb[1]; v[6]=(__bf16)vb[2]; v[7]=(__bf16)vb[3];
        *(bf16x8*)&Xp[(((m >> 5) * 9 + (c >> 1)) * 64 + (c & 1) * 32 + (m & 31)) * 8] = v;
    }
    // ks=8 bias column: k=128 -> 1.0, k=129..143 -> 0
    if (t < 128) {
        int mtx = t >> 6, l = t & 63;
        bf16x8 v;
        #pragma unroll
        for (int j = 0; j < 8; ++j) v[j] = (__bf16)0.f;
        if (l < 32) v[0] = (__bf16)1.0f;
        *(bf16x8*)&Xp[((mtx * 9 + 8) * 64 + l) * 8] = v;
    }
    __syncthreads();

    // ---- router layer 1 (fp64): thread (tok=t&63, rq=(t>>6)*4) -> 4 rf ----
    {
        const int tok = t & 63;
        const int rq  = (t >> 6) * 4;
        const int rqs = __builtin_amdgcn_readfirstlane(rq);  // force s_loads
        double rf4[4];
        #pragma unroll
        for (int j = 0; j < 4; ++j) rf4[j] = br1d[rqs + j];
        const float* xr = xs + tok * 130;
        #pragma unroll 4
        for (int c = 0; c < 64; ++c) {
            f32x2 xv2 = *(const f32x2*)(xr + c * 2);
            #pragma unroll
            for (int q = 0; q < 2; ++q) {
                double xv = (double)xv2[q];
                int k = c * 2 + q;
                #pragma unroll
                for (int j = 0; j < 4; ++j)
                    rf4[j] = fma(xv, wr1d[k * 16 + rqs + j], rf4[j]);
            }
        }
        #pragma unroll
        for (int j = 0; j < 4; ++j)
            rfs[tok * 16 + rq + j] = rf4[j] > 0.0 ? rf4[j] : 0.0;
    }
    __syncthreads();

    // ---- router layer 2 + softmax + div-free mask (fp64), 1 thr/token ----
    if (t < 64) {
        double lg[8];
        #pragma unroll
        for (int j = 0; j < 8; ++j) lg[j] = br2d[j];
        #pragma unroll
        for (int r = 0; r < 16; ++r) {
            double rv = rfs[t * 16 + r];
            #pragma unroll
            for (int j = 0; j < 8; ++j)
                lg[j] = fma(rv, wr2d[r * 8 + j], lg[j]);
        }
        double mx = lg[0];
        #pragma unroll
        for (int j = 1; j < 8; ++j) mx = lg[j] > mx ? lg[j] : mx;
        double ex[8]; double s = 0.0;
        #pragma unroll
        for (int j = 0; j < 8; ++j) { ex[j] = exp(lg[j] - mx); s += ex[j]; }
        // mask: g > 1/8  <=>  8*ex[j] > s   (exact in fp64 up to ~1ulp at 0.125)
        double ms = 0.0;
        bool mk[8];
        #pragma unroll
        for (int j = 0; j < 8; ++j) {
            mk[j] = (8.0 * ex[j] > s);
            ms += mk[j] ? ex[j] : 0.0;
        }
        // mg = ex*m / (sum ex*m + s*1e-8): single fp64 division
        double inv = 1.0 / (ms + s * 1e-8);
        #pragma unroll
        for (int j = 0; j < 8; ++j)
            mgs[t * 8 + j] = mk[j] ? (float)(ex[j] * inv) : 0.f;
    }
    __syncthreads();

    // ---- per-token gates for this wave's token tile ----
    const float* mgr = mgs + (32 * mt + l31) * 8;
    f32x4 ga4 = *(const f32x4*)mgr;
    f32x4 gb4 = *(const f32x4*)(mgr + 4);
    float gte[8] = {ga4[0], ga4[1], ga4[2], ga4[3], gb4[0], gb4[1], gb4[2], gb4[3]};

    f32x16 acc[4];
    #pragma unroll
    for (int ot = 0; ot < 4; ++ot)
        #pragma unroll
        for (int i = 0; i < 16; ++i) acc[ot][i] = 0.f;

    const bf16x8* w1v = (const bf16x8*)w1p;
    const bf16x8* w2v = (const bf16x8*)w2p;

    // double-buffered W1 A-frags: wbuf[n2] used in phase n2; during phase n2
    // we prefetch wbuf[n2^1] for the next phase (n2=1 of same e, or e+1 n2=0)
    bf16x8 wbuf[2][9];
    {
        const bf16x8* p = w1v + ((size_t)(2 * h) * 9) * 64 + lane;
        #pragma unroll
        for (int ks = 0; ks < 9; ++ks) wbuf[0][ks] = p[ks * 64];
    }

    #pragma unroll 1
    for (int e = 0; e < 10; ++e) {
        const float gv = (e < 8) ? gte[e] : 1.0f;
        #pragma unroll
        for (int n2 = 0; n2 < 2; ++n2) {
            // W2 B-frags for this phase: 4 ot x kq={2n2, 2n2+1}
            const bf16x8* wBp = w2v + ((size_t)(e * 4) * 8 + 4 * h + 2 * n2) * 64 + lane;
            bf16x8 wBc[8];
            #pragma unroll
            for (int ot = 0; ot < 4; ++ot)
                #pragma unroll
                for (int b = 0; b < 2; ++b)
                    wBc[ot * 2 + b] = wBp[(ot * 8 + b) * 64];

            // GEMM1 phase: n-tile (2h + n2), weights already in wbuf[n2]
            f32x16 a1;
            #pragma unroll
            for (int i = 0; i < 16; ++i) a1[i] = 0.f;
            #pragma unroll
            for (int ks = 0; ks < 9; ++ks) {
                bf16x8 xb = *(const bf16x8*)&Xp[((mt * 9 + ks) * 64 + lane) * 8];
                a1 = mfma32(wbuf[n2][ks], xb, a1);
            }

            // prefetch next phase's W1 frags (latency hides under gelu+GEMM2)
            {
                int en  = (n2 == 0) ? e : (e < 9 ? e + 1 : 9);
                int ntn = (n2 == 0) ? (2 * h + 1) : (2 * h);
                const bf16x8* p = w1v + ((size_t)(en * 4 + ntn) * 9) * 64 + lane;
                #pragma unroll
                for (int ks = 0; ks < 9; ++ks) wbuf[n2 ^ 1][ks] = p[ks * 64];
            }

            // gelu + gate -> A-frags -> GEMM2
            #pragma unroll
            for (int b = 0; b < 2; ++b) {
                bf16x8 fr;
                #pragma unroll
                for (int jp = 0; jp < 4; ++jp) {
                    f32x2 hh; hh[0] = a1[8 * b + 2 * jp]; hh[1] = a1[8 * b + 2 * jp + 1];
                    f32x2 tt = hh * hh;
                    f32x2 pp;
                    pp[0] = fmaf(tt[0], -GELU_C2, -GELU_C1);
                    pp[1] = fmaf(tt[1], -GELU_C2, -GELU_C1);
                    f32x2 mm = hh * pp;
                    float e0 = __builtin_amdgcn_exp2f(mm[0]);
                    float e1 = __builtin_amdgcn_exp2f(mm[1]);
                    float q0 = __builtin_amdgcn_rcpf(1.f + e0);
                    float q1 = __builtin_amdgcn_rcpf(1.f + e1);
                    f32x2 gg; gg[0] = hh[0] * q0 * gv; gg[1] = hh[1] * q1 * gv;
                    fr[2 * jp]     = (__bf16)gg[0];
                    fr[2 * jp + 1] = (__bf16)gg[1];
                }
                acc[0] = mfma32(fr, wBc[0 * 2 + b], acc[0]);
                acc[1] = mfma32(fr, wBc[1 * 2 + b], acc[1]);
                acc[2] = mfma32(fr, wBc[2 * 2 + b], acc[2]);
                acc[3] = mfma32(fr, wBc[3 * 2 + b], acc[3]);
            }
        }
    }

    __syncthreads();   // all waves done with xs/Xp; Red overlay now safe
    if (h == 1) {
        #pragma unroll
        for (int ot = 0; ot < 4; ++ot)
            #pragma unroll
            for (int r = 0; r < 16; ++r)
                Red[((mt * 4 + ot) * 16 + r) * 64 + lane] = acc[ot][r];
    }
    __syncthreads();
    if (h == 0) {
        float be2c[4][8], bsc[4];
        #pragma unroll
        for (int ot = 0; ot < 4; ++ot) {
            int o = 32 * ot + l31;
            bsc[ot] = bs2[o] + bs2[128 + o];
            #pragma unroll
            for (int ee = 0; ee < 8; ++ee) be2c[ot][ee] = be2[ee * 128 + o];
        }
        const float* mgb = mgs + (32 * mt) * 8;
        #pragma unroll
        for (int r = 0; r < 16; ++r) {
            int mrow = (r & 3) + 8 * (r >> 2) + 4 * lh;
            f32x4 g0 = *(const f32x4*)&mgb[mrow * 8];
            f32x4 g1 = *(const f32x4*)&mgb[mrow * 8 + 4];
            size_t orow = (size_t)(tok0 + 32 * mt + mrow) * 128;
            #pragma unroll
            for (int ot = 0; ot < 4; ++ot) {
                float b = bsc[ot];
                #pragma unroll
                for (int ee = 0; ee < 4; ++ee) b = fmaf(g0[ee], be2c[ot][ee], b);
                #pragma unroll
                for (int ee = 0; ee < 4; ++ee) b = fmaf(g1[ee], be2c[ot][4 + ee], b);
                float v = acc[ot][r] + Red[((mt * 4 + ot) * 16 + r) * 64 + lane] + b;
                out[orow + 32 * ot + l31] = v;
            }
        }
    }
}

// ---------------------------------------------------------------------------
extern "C" void kernel_launch(void* const* d_in, const int* in_sizes, int n_in,
                              void* d_out, int out_size, void* d_ws, size_t ws_size,
                              hipStream_t stream)
{
    const float* x   = (const float*)d_in[0];
    const float* Wr1 = (const float*)d_in[1];
    const float* br1 = (const float*)d_in[2];
    const float* Wr2 = (const float*)d_in[3];
    const float* br2 = (const float*)d_in[4];
    const float* We1 = (const float*)d_in[5];
    const float* be1 = (const float*)d_in[6];
    const float* We2 = (const float*)d_in[7];
    const float* be2 = (const float*)d_in[8];
    const float* Ws1 = (const float*)d_in[9];
    const float* bs1 = (const float*)d_in[10];
    const float* Ws2 = (const float*)d_in[11];
    const float* bs2 = (const float*)d_in[12];

    // ws: [0,368640) W1p bf16; [368640,696320) W2p bf16; then fp64 router
    // weights: wr1d 16384 B, wr2d 1024 B, br1d 128 B, br2d 64 B
    __bf16* w1p  = (__bf16*)d_ws;
    __bf16* w2p  = (__bf16*)((char*)d_ws + 368640);
    double* wr1d = (double*)((char*)d_ws + 696320);
    double* wr2d = (double*)((char*)d_ws + 712704);
    double* br1d = (double*)((char*)d_ws + 713728);
    double* br2d = (double*)((char*)d_ws + 713856);

    pack_kernel<<<179, 256, 0, stream>>>(We1, be1, Ws1, bs1, We2, Ws2,
                                         Wr1, br1, Wr2, br2,
                                         w1p, w2p, wr1d, br1d, wr2d, br2d);
    moe_main_kernel<<<1024, 256, 0, stream>>>(x, wr1d, br1d, wr2d, br2d,
                                              w1p, w2p, be2, bs2, (float*)d_out);
}